// Round 10
// baseline (416.980 us; speedup 1.0000x reference)
//
#include <hip/hip_runtime.h>
#include <hip/hip_bf16.h>
#include <cstdint>
#include <cmath>

// ResMoELoRALinear fused as ONE bf16 GEMM with augmented K:
//   out[8192,4096] = [x_bf16 | P] (8192x5120) @ [W_base | Bflat]^T (4096x5120) + b_base
// r10: gemm restructured to 2 phases/tile: P1 = {stage ALL of tile T+1 (8
// gloads) ; read ALL 24 fragments ; BAR ; lgkm0 ; 32 MFMA}, P2 = {vmcnt(0)
// [drains loads issued >=1 phase ago — benign] ; BAR ; 32 MFMA}. Barriers
// 4->2/tile; formal +2-phase stage-after-read gap preserved (all buf reads
// live in P1, stages issued after the NEXT tile's BAR_b). af[8][2] (+32 VGPR,
// still 1 block/CU — LDS-bound). build_msp/prep_fused identical to r9.

#define M_TOT 8192
#define N_OUT 4096
#define K_IN  4096
#define K_TOT 5120
#define NEXP  16
#define NRES  64
#define NT    (K_TOT / 64)   // 80 K-tiles
#define NCH   (K_IN / 64)    // 64 prep chunks

typedef __bf16 bf16x8 __attribute__((ext_vector_type(8)));
typedef float  f32x4  __attribute__((ext_vector_type(4)));
using u16 = unsigned short;

__device__ __forceinline__ u16 bfbits(float f) {
  __bf16 h = (__bf16)f;
  union { __bf16 h; u16 u; } c; c.h = h;
  return c.u;
}
__device__ __forceinline__ float lopart(float f) {
  __bf16 h = (__bf16)f;
  return f - (float)h;
}

__device__ __forceinline__ void gload_lds16(const void* g, void* l) {
  const __attribute__((address_space(1))) unsigned* gp =
      (const __attribute__((address_space(1))) unsigned*)(unsigned long long)(uintptr_t)g;
  __attribute__((address_space(3))) unsigned* lp =
      (__attribute__((address_space(3))) unsigned*)(unsigned)(uintptr_t)l;
  __builtin_amdgcn_global_load_lds(gp, lp, 16, 0, 0);
}

#define MFMA16 __builtin_amdgcn_mfma_f32_16x16x32_bf16

// ------- Kernel 1: Msp emit only (96 blocks) -------
__global__ __launch_bounds__(256) void build_msp(const float* __restrict__ Wr,
                                                 const float* __restrict__ Amat,
                                                 u16* __restrict__ Msp) {
  const int row = blockIdx.x;               // 0..95
  const int tid = threadIdx.x;
  const float* src = (row < 16) ? (Wr + (size_t)row * K_IN)
                   : (row < 80) ? (Amat + (size_t)(row - 16) * K_IN)
                                : (Wr + (size_t)(row - 80) * K_IN);
  const bool lo = (row >= 80);
#pragma unroll
  for (int it = 0; it < 2; ++it) {
    int gi = tid + it * 256;                // granule 0..511
    int col = gi * 8;
    float4 a = *(const float4*)(src + col);
    float4 b = *(const float4*)(src + col + 4);
    float v0 = a.x, v1 = a.y, v2 = a.z, v3 = a.w;
    float v4 = b.x, v5 = b.y, v6 = b.z, v7 = b.w;
    if (lo) { v0 = lopart(v0); v1 = lopart(v1); v2 = lopart(v2); v3 = lopart(v3);
              v4 = lopart(v4); v5 = lopart(v5); v6 = lopart(v6); v7 = lopart(v7); }
    ushort4 o0, o1;
    o0.x = bfbits(v0); o0.y = bfbits(v1); o0.z = bfbits(v2); o0.w = bfbits(v3);
    o1.x = bfbits(v4); o1.y = bfbits(v5); o1.z = bfbits(v6); o1.w = bfbits(v7);
    u16* dst = Msp + ((size_t)(((gi >> 3) * 96 + row) * 8 + ((gi & 7) ^ (row & 7)))) * 8;
    *(ushort4*)(dst) = o0;
    *(ushort4*)(dst + 4) = o1;
  }
}

// ---- Kernel 2: FUSED prep (blocks 0-255) + Wa conversion (blocks 256-4351) ----
#define PSTR 72
#define BUF_U16 10752

__global__ __launch_bounds__(256) void prep_fused(const float* __restrict__ x,
                                                  const u16* __restrict__ Msp,
                                                  const int* __restrict__ topk_p,
                                                  const float* __restrict__ Wb,
                                                  const float* __restrict__ Bm,
                                                  u16* __restrict__ Xa,
                                                  u16* __restrict__ Wa) {
  __shared__ __align__(16) u16 smem[2 * BUF_U16];
  const int tid = threadIdx.x;

  if (blockIdx.x >= 256) {
    const int d = blockIdx.x - 256;
#pragma unroll
    for (int it = 0; it < 5; ++it) {
      int j = tid + it * 256;
      int kcol = j * 4;
      float4 v;
      if (kcol < K_IN) {
        v = *(const float4*)(Wb + (size_t)d * K_IN + kcol);
      } else {
        int kk = kcol - K_IN;
        int n = kk >> 6, r = kk & 63;
        v = *(const float4*)(Bm + ((size_t)n * N_OUT + d) * NRES + r);
      }
      ushort4 o;
      o.x = bfbits(v.x); o.y = bfbits(v.y); o.z = bfbits(v.z); o.w = bfbits(v.w);
      *(ushort4*)(Wa + (size_t)d * K_TOT + kcol) = o;
    }
    return;
  }

  const int w = tid >> 6, l = tid & 63;
  const int l15 = l & 15, l4 = l >> 4;
  const int rt = w >> 1, cg = w & 1;
  const int token0 = blockIdx.x * 32;

  f32x4 acc[3] = {};

#define STAGE_CHUNK(kc, buf) do {                                              \
    u16* xh_ = smem + (buf) * BUF_U16;                                         \
    u16* xl_ = xh_ + 32 * PSTR;                                                \
    u16* Ms_ = xl_ + 32 * PSTR;                                                \
    const int k0_ = (kc) * 64;                                                 \
    _Pragma("unroll")                                                          \
    for (int it = 0; it < 3; ++it) {                                           \
      gload_lds16(Msp + (size_t)(kc) * 6144 + (size_t)(it * 256 + tid) * 8,    \
                  Ms_ + it * 2048 + w * 512);                                  \
    }                                                                          \
    _Pragma("unroll")                                                          \
    for (int it = 0; it < 2; ++it) {                                           \
      int i_ = tid + it * 256;                                                 \
      int row_ = i_ >> 4, c4_ = (i_ & 15) * 4;                                 \
      float4 v_ = *(const float4*)(x + (size_t)(token0 + row_) * K_IN + k0_ + c4_); \
      ushort4 h_;                                                              \
      h_.x = bfbits(v_.x); h_.y = bfbits(v_.y);                                \
      h_.z = bfbits(v_.z); h_.w = bfbits(v_.w);                                \
      ushort4 lo_;                                                             \
      lo_.x = bfbits(lopart(v_.x)); lo_.y = bfbits(lopart(v_.y));              \
      lo_.z = bfbits(lopart(v_.z)); lo_.w = bfbits(lopart(v_.w));              \
      *(ushort4*)&xh_[row_ * PSTR + c4_] = h_;                                 \
      *(ushort4*)&xl_[row_ * PSTR + c4_] = lo_;                                \
      *(ushort4*)(Xa + (size_t)(token0 + row_) * K_TOT + k0_ + c4_) = h_;      \
    }                                                                          \
  } while (0)

#define MS_FRAG(Ms_, tb, ks) \
  (*(const bf16x8*)&(Ms_)[(size_t)((((tb) * 16 + l15) * 8 + (((ks) * 4 + l4) ^ (l15 & 7)))) * 8])

  STAGE_CHUNK(0, 0);
  __syncthreads();

  for (int kc = 0; kc < NCH; ++kc) {
    const int cur = kc & 1;
    if (kc + 1 < NCH) {
      if ((kc + 1) & 1) STAGE_CHUNK(kc + 1, 1);
      else              STAGE_CHUNK(kc + 1, 0);
    }
    {
      const u16* xh_ = smem + cur * BUF_U16;
      const u16* xl_ = xh_ + 32 * PSTR;
      const u16* Ms_ = xl_ + 32 * PSTR;
      const int arow = (rt * 16 + l15) * PSTR;
#pragma unroll
      for (int ks = 0; ks < 2; ++ks) {
        const int fo = ks * 32 + l4 * 8;
        const bf16x8 ah = *(const bf16x8*)&xh_[arow + fo];
        if (cg == 0) {
          const bf16x8 al = *(const bf16x8*)&xl_[arow + fo];
          const bf16x8 b0 = MS_FRAG(Ms_, 0, ks);
          const bf16x8 b1 = MS_FRAG(Ms_, 1, ks);
          const bf16x8 b5 = MS_FRAG(Ms_, 5, ks);
          acc[0] = MFMA16(ah, b0, acc[0], 0, 0, 0);
          acc[0] = MFMA16(al, b0, acc[0], 0, 0, 0);
          acc[0] = MFMA16(ah, b5, acc[0], 0, 0, 0);
          acc[1] = MFMA16(ah, b1, acc[1], 0, 0, 0);
        } else {
          const bf16x8 b2 = MS_FRAG(Ms_, 2, ks);
          const bf16x8 b3 = MS_FRAG(Ms_, 3, ks);
          const bf16x8 b4 = MS_FRAG(Ms_, 4, ks);
          acc[0] = MFMA16(ah, b2, acc[0], 0, 0, 0);
          acc[1] = MFMA16(ah, b3, acc[1], 0, 0, 0);
          acc[2] = MFMA16(ah, b4, acc[2], 0, 0, 0);
        }
      }
    }
    __syncthreads();
  }

  float* arr  = (float*)smem;                       // [32][80]
  float* wexp = (float*)((char*)smem + 10240);      // [32][16]
  {
    const int row0 = rt * 16 + l4 * 4;
    if (cg == 0) {
#pragma unroll
      for (int ct = 0; ct < 2; ++ct)
#pragma unroll
        for (int j = 0; j < 4; ++j)
          arr[(row0 + j) * 80 + ct * 16 + l15] = acc[ct][j];
    } else {
#pragma unroll
      for (int ct = 0; ct < 3; ++ct)
#pragma unroll
        for (int j = 0; j < 4; ++j)
          arr[(row0 + j) * 80 + 32 + ct * 16 + l15] = acc[ct][j];
    }
  }
  __syncthreads();

  if (tid < 32) {
    const int tt = tid;
    const int k = *topk_p;
    float p[16];
    float mx = arr[tt * 80 + 0];
#pragma unroll
    for (int e = 1; e < 16; ++e) mx = fmaxf(mx, arr[tt * 80 + e]);
    float Z = 0.f;
#pragma unroll
    for (int e = 0; e < 16; ++e) { p[e] = expf(arr[tt * 80 + e] - mx); Z += p[e]; }
    const float invZ = 1.f / Z;
#pragma unroll
    for (int e = 0; e < 16; ++e) p[e] *= invZ;
    float wv[16];
    if (k <= 0 || k >= NEXP) {
#pragma unroll
      for (int e = 0; e < 16; ++e) wv[e] = p[e];
    } else {
      unsigned um = 0; float ssum = 0.f;
      for (int kk = 0; kk < k; ++kk) {
        int best = 0; float bv = -1.f;
#pragma unroll
        for (int e = 0; e < 16; ++e)
          if (!((um >> e) & 1u) && p[e] > bv) { bv = p[e]; best = e; }
        um |= 1u << best; ssum += bv;
      }
      const float inv = 1.f / (ssum + 1e-6f);
#pragma unroll
      for (int e = 0; e < 16; ++e) wv[e] = ((um >> e) & 1u) ? p[e] * inv : 0.f;
    }
#pragma unroll
    for (int e = 0; e < 16; ++e) wexp[tt * 16 + e] = wv[e];
  }
  __syncthreads();

#pragma unroll
  for (int it = 0; it < 16; ++it) {
    int idx = tid + it * 256;
    int tt = idx >> 7, c8 = idx & 127;
    int n = c8 >> 3, r0 = (c8 & 7) * 8;
    const float wv = wexp[tt * 16 + n];
    const float* hb = &arr[tt * 80 + 16 + r0];
    ushort4 lo, hi;
    lo.x = bfbits(wv * hb[0]); lo.y = bfbits(wv * hb[1]);
    lo.z = bfbits(wv * hb[2]); lo.w = bfbits(wv * hb[3]);
    hi.x = bfbits(wv * hb[4]); hi.y = bfbits(wv * hb[5]);
    hi.z = bfbits(wv * hb[6]); hi.w = bfbits(wv * hb[7]);
    u16* dst = Xa + (size_t)(token0 + tt) * K_TOT + K_IN + c8 * 8;
    *(ushort4*)(dst) = lo;
    *(ushort4*)(dst + 4) = hi;
  }
}

// ------ Kernel 3 (r10): 256^2 GEMM, 2 phases/tile ------
// P1: {stage tile T+1 (8 gloads) ; read 24 frags ; BAR ; lgkm0 ; 32 MFMA n0,1}
// P2: {vmcnt(0) [old loads only] ; BAR ; 32 MFMA n2,3}
// LDS (u16): buf b*32768 ; A +0 / B +16384 ; half +8192 ; row*64.
#define PHASE_BAR() do {                      \
  __builtin_amdgcn_sched_barrier(0);          \
  __builtin_amdgcn_s_barrier();               \
  __builtin_amdgcn_sched_barrier(0);          \
} while (0)

#define LGKM0() do {                          \
  asm volatile("s_waitcnt lgkmcnt(0)");       \
  __builtin_amdgcn_sched_barrier(0);          \
} while (0)

__global__ __launch_bounds__(512, 2) void gemm_aug(const u16* __restrict__ Xa,
                                                   const u16* __restrict__ Wa,
                                                   const float* __restrict__ bias,
                                                   float* __restrict__ out) {
  extern __shared__ u16 lds[];
  const int tid = threadIdx.x;
  const int w = tid >> 6, l = tid & 63;
  const int bid = blockIdx.x;
  const int wg = (bid & 7) * 64 + (bid >> 3);     // T1: XCD-bijective (512%8==0)
  const int bm = wg >> 4, bn = wg & 15;
  const int wm = w >> 2, wn = w & 3;

  const int srow = w * 8 + (l >> 3);
  const int gsw = ((l & 7) ^ (l >> 3)) * 8;       // pre-swizzled global granule
  const u16* sA = Xa + (size_t)(bm * 256 + srow) * K_TOT + gsw;
  const u16* sB = Wa + (size_t)(bn * 256 + srow) * K_TOT + gsw;
  const int stq = w * 512;

  const int arow = (l & 15) * 64;
  const int c0 = (((l >> 4) + 0) ^ (l & 7)) * 8;
  const int c1 = (((l >> 4) + 4) ^ (l & 7)) * 8;

  f32x4 acc[8][4] = {};

#define STAGE_A2(tile, half, bufc) do {                                        \
    const u16* s_ = sA + (size_t)(half) * 128 * K_TOT + (size_t)(tile) * 64;   \
    const int d_ = (bufc) * 32768 + (half) * 8192 + stq;                       \
    gload_lds16(s_, &lds[d_]);                                                 \
    gload_lds16(s_ + (size_t)64 * K_TOT, &lds[d_ + 4096]);                     \
  } while (0)
#define STAGE_B2(tile, half, bufc) do {                                        \
    const u16* s_ = sB + (size_t)(half) * 128 * K_TOT + (size_t)(tile) * 64;   \
    const int d_ = (bufc) * 32768 + 16384 + (half) * 8192 + stq;               \
    gload_lds16(s_, &lds[d_]);                                                 \
    gload_lds16(s_ + (size_t)64 * K_TOT, &lds[d_ + 4096]);                     \
  } while (0)

  // prologue: stage tile 0 only; drain; barrier.
  STAGE_B2(0, 0, 0); STAGE_B2(0, 1, 0); STAGE_A2(0, 0, 0); STAGE_A2(0, 1, 0);
  __builtin_amdgcn_sched_barrier(0);
  asm volatile("s_waitcnt vmcnt(0)");
  PHASE_BAR();

#define DO_TILE(TT, BUFC) do {                                                 \
    const int aoff_ = (BUFC) * 32768 + wm * 8192;                              \
    const int boff_ = (BUFC) * 32768 + 16384 + (wn >> 1) * 8192 + (wn & 1) * 4096; \
    bf16x8 af[8][2], b0f[2][2], b1f[2][2];                                     \
    /* P1: stage ALL of tile TT+1 (issue-early), read ALL 24 frags */          \
    if ((TT) + 1 < NT) {                                                       \
      STAGE_B2((TT) + 1, 0, (BUFC) ^ 1);                                       \
      STAGE_B2((TT) + 1, 1, (BUFC) ^ 1);                                       \
      STAGE_A2((TT) + 1, 0, (BUFC) ^ 1);                                       \
      STAGE_A2((TT) + 1, 1, (BUFC) ^ 1);                                       \
    }                                                                          \
    _Pragma("unroll")                                                          \
    for (int m = 0; m < 8; ++m) {                                              \
      af[m][0] = *(const bf16x8*)&lds[aoff_ + m * 1024 + arow + c0];           \
      af[m][1] = *(const bf16x8*)&lds[aoff_ + m * 1024 + arow + c1];           \
    }                                                                          \
    _Pragma("unroll")                                                          \
    for (int n = 0; n < 2; ++n) {                                              \
      b0f[n][0] = *(const bf16x8*)&lds[boff_ + n * 1024 + arow + c0];          \
      b0f[n][1] = *(const bf16x8*)&lds[boff_ + n * 1024 + arow + c1];          \
      b1f[n][0] = *(const bf16x8*)&lds[boff_ + (n + 2) * 1024 + arow + c0];    \
      b1f[n][1] = *(const bf16x8*)&lds[boff_ + (n + 2) * 1024 + arow + c1];    \
    }                                                                          \
    PHASE_BAR(); LGKM0();                                                      \
    __builtin_amdgcn_s_setprio(1);                                             \
    _Pragma("unroll")                                                          \
    for (int m = 0; m < 8; ++m)                                                \
      _Pragma("unroll")                                                        \
      for (int n = 0; n < 2; ++n) {                                            \
        acc[m][n] = MFMA16(af[m][0], b0f[n][0], acc[m][n], 0, 0, 0);           \
        acc[m][n] = MFMA16(af[m][1], b0f[n][1], acc[m][n], 0, 0, 0);           \
      }                                                                        \
    __builtin_amdgcn_s_setprio(0);                                             \
    /* P2: wait tile TT+1 landed (loads are >=1 phase old), BAR, MFMA n2,3 */  \
    __builtin_amdgcn_sched_barrier(0);                                         \
    asm volatile("s_waitcnt vmcnt(0)");                                        \
    PHASE_BAR();                                                               \
    __builtin_amdgcn_s_setprio(1);                                             \
    _Pragma("unroll")                                                          \
    for (int m = 0; m < 8; ++m)                                                \
      _Pragma("unroll")                                                        \
      for (int n = 0; n < 2; ++n) {                                            \
        acc[m][n + 2] = MFMA16(af[m][0], b1f[n][0], acc[m][n + 2], 0, 0, 0);   \
        acc[m][n + 2] = MFMA16(af[m][1], b1f[n][1], acc[m][n + 2], 0, 0, 0);   \
      }                                                                        \
    __builtin_amdgcn_s_setprio(0);                                             \
  } while (0)

  for (int t = 0; t < NT; t += 2) {
    DO_TILE(t, 0);
    DO_TILE(t + 1, 1);
  }

  // ---- epilogue: C/D layout col=lane&15, row=(lane>>4)*4+reg ----
  const int colBase = bn * 256 + wn * 64 + (l & 15);
  float bv[4];
#pragma unroll
  for (int n = 0; n < 4; ++n) bv[n] = bias[colBase + n * 16];
#pragma unroll
  for (int mi = 0; mi < 8; ++mi) {
    const int row = bm * 256 + wm * 128 + mi * 16 + (l >> 4) * 4;
#pragma unroll
    for (int j = 0; j < 4; ++j) {
      float* orow = out + (size_t)(row + j) * N_OUT + colBase;
#pragma unroll
      for (int n = 0; n < 4; ++n) orow[n * 16] = acc[mi][n][j] + bv[n];
    }
  }
}

extern "C" void kernel_launch(void* const* d_in, const int* in_sizes, int n_in,
                              void* d_out, int out_size, void* d_ws, size_t ws_size,
                              hipStream_t stream) {
  const float* x  = (const float*)d_in[0];
  const float* Wb = (const float*)d_in[1];
  const float* bb = (const float*)d_in[2];
  const float* Am = (const float*)d_in[3];
  const float* Bm = (const float*)d_in[4];
  const float* Wr = (const float*)d_in[5];
  const int* topk = (const int*)d_in[6];
  float* out = (float*)d_out;

  u16* Xa  = (u16*)d_ws;                          // 8192*5120 bf16
  u16* Wa  = Xa + (size_t)M_TOT * K_TOT;          // 4096*5120 bf16
  u16* Msp = Wa + (size_t)N_OUT * K_TOT;          // 64*96*64 bf16 (786 KB)

  (void)hipFuncSetAttribute((const void*)gemm_aug,
                            hipFuncAttributeMaxDynamicSharedMemorySize, 131072);

  hipLaunchKernelGGL(build_msp,  dim3(96),          dim3(256), 0, stream,
                     Wr, Am, Msp);
  hipLaunchKernelGGL(prep_fused, dim3(256 + N_OUT), dim3(256), 0, stream,
                     x, Msp, topk, Wb, Bm, Xa, Wa);
  hipLaunchKernelGGL(gemm_aug,   dim3(512),         dim3(512), 131072, stream,
                     Xa, Wa, bb, out);
}

// Round 11
// 363.477 us; speedup vs baseline: 1.1472x; 1.1472x over previous
//
#include <hip/hip_runtime.h>
#include <hip/hip_bf16.h>
#include <cstdint>
#include <cmath>

// ResMoELoRALinear fused as ONE bf16 GEMM with augmented K:
//   out[8192,4096] = [x_bf16 | P] (8192x5120) @ [W_base | Bflat]^T (4096x5120) + b_base
// r11: gemm REVERTED to r8's proven 4-phase/1-barrier schedule (272us stable;
// r10's 2-phase drain-all regressed: vmcnt(0) ~160cyc after issue exposed HBM
// latency every tile). Pre-stage upgraded: prep blocks 8 waves / 64 tokens
// (128 blocks) for 2x latency-hiding TLP; Wa conversion 2 rows/block on the
// other 2048 blocks, fully concurrent. build_msp unchanged.

#define M_TOT 8192
#define N_OUT 4096
#define K_IN  4096
#define K_TOT 5120
#define NEXP  16
#define NRES  64
#define NT    (K_TOT / 64)   // 80 K-tiles
#define NCH   (K_IN / 64)    // 64 prep chunks

typedef __bf16 bf16x8 __attribute__((ext_vector_type(8)));
typedef float  f32x4  __attribute__((ext_vector_type(4)));
using u16 = unsigned short;

__device__ __forceinline__ u16 bfbits(float f) {
  __bf16 h = (__bf16)f;
  union { __bf16 h; u16 u; } c; c.h = h;
  return c.u;
}
__device__ __forceinline__ float lopart(float f) {
  __bf16 h = (__bf16)f;
  return f - (float)h;
}

__device__ __forceinline__ void gload_lds16(const void* g, void* l) {
  const __attribute__((address_space(1))) unsigned* gp =
      (const __attribute__((address_space(1))) unsigned*)(unsigned long long)(uintptr_t)g;
  __attribute__((address_space(3))) unsigned* lp =
      (__attribute__((address_space(3))) unsigned*)(unsigned)(uintptr_t)l;
  __builtin_amdgcn_global_load_lds(gp, lp, 16, 0, 0);
}

#define MFMA16 __builtin_amdgcn_mfma_f32_16x16x32_bf16

// ------- Kernel 1: Msp emit only (96 blocks) -------
// Msp layout: [chunk 64][row 96][g 8][e 8] u16, stored granule g' = g^(row&7).
// rows 0-15 = WrHi, 16-79 = A, 80-95 = WrLo.
__global__ __launch_bounds__(256) void build_msp(const float* __restrict__ Wr,
                                                 const float* __restrict__ Amat,
                                                 u16* __restrict__ Msp) {
  const int row = blockIdx.x;               // 0..95
  const int tid = threadIdx.x;
  const float* src = (row < 16) ? (Wr + (size_t)row * K_IN)
                   : (row < 80) ? (Amat + (size_t)(row - 16) * K_IN)
                                : (Wr + (size_t)(row - 80) * K_IN);
  const bool lo = (row >= 80);
#pragma unroll
  for (int it = 0; it < 2; ++it) {
    int gi = tid + it * 256;                // granule 0..511
    int col = gi * 8;
    float4 a = *(const float4*)(src + col);
    float4 b = *(const float4*)(src + col + 4);
    float v0 = a.x, v1 = a.y, v2 = a.z, v3 = a.w;
    float v4 = b.x, v5 = b.y, v6 = b.z, v7 = b.w;
    if (lo) { v0 = lopart(v0); v1 = lopart(v1); v2 = lopart(v2); v3 = lopart(v3);
              v4 = lopart(v4); v5 = lopart(v5); v6 = lopart(v6); v7 = lopart(v7); }
    ushort4 o0, o1;
    o0.x = bfbits(v0); o0.y = bfbits(v1); o0.z = bfbits(v2); o0.w = bfbits(v3);
    o1.x = bfbits(v4); o1.y = bfbits(v5); o1.z = bfbits(v6); o1.w = bfbits(v7);
    u16* dst = Msp + ((size_t)(((gi >> 3) * 96 + row) * 8 + ((gi & 7) ^ (row & 7)))) * 8;
    *(ushort4*)(dst) = o0;
    *(ushort4*)(dst + 4) = o1;
  }
}

// ---- Kernel 2 (r11): FUSED prep (blocks 0-127, 8 waves, 64 tokens/block)
//      + Wa conversion (blocks 128-2175, 2 rows/block). 512 threads. ----
#define PSTR 72
#define BUF_U16 15360   // xh 64*72 + xl 64*72 + Ms 6144

__global__ __launch_bounds__(512) void prep_fused(const float* __restrict__ x,
                                                  const u16* __restrict__ Msp,
                                                  const int* __restrict__ topk_p,
                                                  const float* __restrict__ Wb,
                                                  const float* __restrict__ Bm,
                                                  u16* __restrict__ Xa,
                                                  u16* __restrict__ Wa) {
  __shared__ __align__(16) u16 smem[2 * BUF_U16];   // 61440 B
  const int tid = threadIdx.x;

  if (blockIdx.x >= 128) {
    // ---- Wa conversion: 2 rows per block ----
    const int d = (blockIdx.x - 128) * 2 + (tid >> 8);
    const int t8 = tid & 255;
#pragma unroll
    for (int it = 0; it < 5; ++it) {
      int j = t8 + it * 256;
      int kcol = j * 4;
      float4 v;
      if (kcol < K_IN) {
        v = *(const float4*)(Wb + (size_t)d * K_IN + kcol);
      } else {
        int kk = kcol - K_IN;
        int n = kk >> 6, r = kk & 63;
        v = *(const float4*)(Bm + ((size_t)n * N_OUT + d) * NRES + r);
      }
      ushort4 o;
      o.x = bfbits(v.x); o.y = bfbits(v.y); o.z = bfbits(v.z); o.w = bfbits(v.w);
      *(ushort4*)(Wa + (size_t)d * K_TOT + kcol) = o;
    }
    return;
  }

  // ---- prep path: 64 tokens/block, 8 waves, K-chunks of 64 ----
  const int w = tid >> 6, l = tid & 63;
  const int l15 = l & 15, l4 = l >> 4;
  const int rt = w >> 1, cg = w & 1;          // rt 0..3 (16 tokens each), cg 0/1
  const int token0 = blockIdx.x * 64;

  f32x4 acc[3] = {};

#define STAGE_CHUNK(kc, buf) do {                                              \
    u16* xh_ = smem + (buf) * BUF_U16;                                         \
    u16* xl_ = xh_ + 64 * PSTR;                                                \
    u16* Ms_ = xl_ + 64 * PSTR;                                                \
    const int k0_ = (kc) * 64;                                                 \
    /* Msp DMA: 768 granules = 512 (all waves) + 256 (waves 0-3, full) */      \
    gload_lds16(Msp + (size_t)(kc) * 6144 + (size_t)tid * 8, Ms_ + w * 512);   \
    if (tid < 256)                                                             \
      gload_lds16(Msp + (size_t)(kc) * 6144 + (size_t)(512 + tid) * 8,         \
                  Ms_ + 4096 + w * 512);                                       \
    _Pragma("unroll")                                                          \
    for (int it = 0; it < 2; ++it) {                                           \
      int i_ = tid + it * 512;                                                 \
      int row_ = i_ >> 4, c4_ = (i_ & 15) * 4;                                 \
      float4 v_ = *(const float4*)(x + (size_t)(token0 + row_) * K_IN + k0_ + c4_); \
      ushort4 h_;                                                              \
      h_.x = bfbits(v_.x); h_.y = bfbits(v_.y);                                \
      h_.z = bfbits(v_.z); h_.w = bfbits(v_.w);                                \
      ushort4 lo_;                                                             \
      lo_.x = bfbits(lopart(v_.x)); lo_.y = bfbits(lopart(v_.y));              \
      lo_.z = bfbits(lopart(v_.z)); lo_.w = bfbits(lopart(v_.w));              \
      *(ushort4*)&xh_[row_ * PSTR + c4_] = h_;                                 \
      *(ushort4*)&xl_[row_ * PSTR + c4_] = lo_;                                \
      *(ushort4*)(Xa + (size_t)(token0 + row_) * K_TOT + k0_ + c4_) = h_;      \
    }                                                                          \
  } while (0)

#define MS_FRAG(Ms_, tb, ks) \
  (*(const bf16x8*)&(Ms_)[(size_t)((((tb) * 16 + l15) * 8 + (((ks) * 4 + l4) ^ (l15 & 7)))) * 8])

  STAGE_CHUNK(0, 0);
  __syncthreads();

  for (int kc = 0; kc < NCH; ++kc) {
    const int cur = kc & 1;
    if (kc + 1 < NCH) {
      if ((kc + 1) & 1) STAGE_CHUNK(kc + 1, 1);
      else              STAGE_CHUNK(kc + 1, 0);
    }
    {
      const u16* xh_ = smem + cur * BUF_U16;
      const u16* xl_ = xh_ + 64 * PSTR;
      const u16* Ms_ = xl_ + 64 * PSTR;
      const int arow = (rt * 16 + l15) * PSTR;
#pragma unroll
      for (int ks = 0; ks < 2; ++ks) {
        const int fo = ks * 32 + l4 * 8;
        const bf16x8 ah = *(const bf16x8*)&xh_[arow + fo];
        if (cg == 0) {
          const bf16x8 al = *(const bf16x8*)&xl_[arow + fo];
          const bf16x8 b0 = MS_FRAG(Ms_, 0, ks);
          const bf16x8 b1 = MS_FRAG(Ms_, 1, ks);
          const bf16x8 b5 = MS_FRAG(Ms_, 5, ks);
          acc[0] = MFMA16(ah, b0, acc[0], 0, 0, 0);
          acc[0] = MFMA16(al, b0, acc[0], 0, 0, 0);
          acc[0] = MFMA16(ah, b5, acc[0], 0, 0, 0);
          acc[1] = MFMA16(ah, b1, acc[1], 0, 0, 0);
        } else {
          const bf16x8 b2 = MS_FRAG(Ms_, 2, ks);
          const bf16x8 b3 = MS_FRAG(Ms_, 3, ks);
          const bf16x8 b4 = MS_FRAG(Ms_, 4, ks);
          acc[0] = MFMA16(ah, b2, acc[0], 0, 0, 0);
          acc[1] = MFMA16(ah, b3, acc[1], 0, 0, 0);
          acc[2] = MFMA16(ah, b4, acc[2], 0, 0, 0);
        }
      }
    }
    __syncthreads();
  }

  // ---- epilogue: H -> LDS (overlay buf0), softmax/top-k, P write ----
  float* arr  = (float*)smem;                       // [64][80]
  float* wexp = (float*)((char*)smem + 20480);      // [64][16]
  {
    const int row0 = rt * 16 + l4 * 4;
    if (cg == 0) {
#pragma unroll
      for (int ct = 0; ct < 2; ++ct)
#pragma unroll
        for (int j = 0; j < 4; ++j)
          arr[(row0 + j) * 80 + ct * 16 + l15] = acc[ct][j];
    } else {
#pragma unroll
      for (int ct = 0; ct < 3; ++ct)
#pragma unroll
        for (int j = 0; j < 4; ++j)
          arr[(row0 + j) * 80 + 32 + ct * 16 + l15] = acc[ct][j];
    }
  }
  __syncthreads();

  if (tid < 64) {
    const int tt = tid;
    const int k = *topk_p;
    float p[16];
    float mx = arr[tt * 80 + 0];
#pragma unroll
    for (int e = 1; e < 16; ++e) mx = fmaxf(mx, arr[tt * 80 + e]);
    float Z = 0.f;
#pragma unroll
    for (int e = 0; e < 16; ++e) { p[e] = expf(arr[tt * 80 + e] - mx); Z += p[e]; }
    const float invZ = 1.f / Z;
#pragma unroll
    for (int e = 0; e < 16; ++e) p[e] *= invZ;
    float wv[16];
    if (k <= 0 || k >= NEXP) {
#pragma unroll
      for (int e = 0; e < 16; ++e) wv[e] = p[e];
    } else {
      unsigned um = 0; float ssum = 0.f;
      for (int kk = 0; kk < k; ++kk) {
        int best = 0; float bv = -1.f;
#pragma unroll
        for (int e = 0; e < 16; ++e)
          if (!((um >> e) & 1u) && p[e] > bv) { bv = p[e]; best = e; }
        um |= 1u << best; ssum += bv;
      }
      const float inv = 1.f / (ssum + 1e-6f);
#pragma unroll
      for (int e = 0; e < 16; ++e) wv[e] = ((um >> e) & 1u) ? p[e] * inv : 0.f;
    }
#pragma unroll
    for (int e = 0; e < 16; ++e) wexp[tt * 16 + e] = wv[e];
  }
  __syncthreads();

#pragma unroll
  for (int it = 0; it < 16; ++it) {
    int idx = tid + it * 512;             // 0..8191 over 64 tokens x 128 groups
    int tt = idx >> 7, c8 = idx & 127;
    int n = c8 >> 3, r0 = (c8 & 7) * 8;
    const float wv = wexp[tt * 16 + n];
    const float* hb = &arr[tt * 80 + 16 + r0];
    ushort4 lo, hi;
    lo.x = bfbits(wv * hb[0]); lo.y = bfbits(wv * hb[1]);
    lo.z = bfbits(wv * hb[2]); lo.w = bfbits(wv * hb[3]);
    hi.x = bfbits(wv * hb[4]); hi.y = bfbits(wv * hb[5]);
    hi.z = bfbits(wv * hb[6]); hi.w = bfbits(wv * hb[7]);
    u16* dst = Xa + (size_t)(token0 + tt) * K_TOT + K_IN + c8 * 8;
    *(ushort4*)(dst) = lo;
    *(ushort4*)(dst + 4) = hi;
  }
}

// ------ Kernel 3 (r8, proven, byte-exact): 256^2 GEMM, ONE barrier per phase ------
#define PHASE_BAR() do {                      \
  __builtin_amdgcn_sched_barrier(0);          \
  __builtin_amdgcn_s_barrier();               \
  __builtin_amdgcn_sched_barrier(0);          \
} while (0)

#define LGKM0() do {                          \
  asm volatile("s_waitcnt lgkmcnt(0)");       \
  __builtin_amdgcn_sched_barrier(0);          \
} while (0)

__global__ __launch_bounds__(512, 2) void gemm_aug(const u16* __restrict__ Xa,
                                                   const u16* __restrict__ Wa,
                                                   const float* __restrict__ bias,
                                                   float* __restrict__ out) {
  extern __shared__ u16 lds[];
  const int tid = threadIdx.x;
  const int w = tid >> 6, l = tid & 63;
  const int bid = blockIdx.x;
  const int wg = (bid & 7) * 64 + (bid >> 3);     // T1: XCD-bijective (512%8==0)
  const int bm = wg >> 4, bn = wg & 15;
  const int wm = w >> 2, wn = w & 3;

  const int srow = w * 8 + (l >> 3);
  const int gsw = ((l & 7) ^ (l >> 3)) * 8;       // pre-swizzled global granule
  const u16* sA = Xa + (size_t)(bm * 256 + srow) * K_TOT + gsw;
  const u16* sB = Wa + (size_t)(bn * 256 + srow) * K_TOT + gsw;
  const int stq = w * 512;

  const int arow = (l & 15) * 64;
  const int c0 = (((l >> 4) + 0) ^ (l & 7)) * 8;
  const int c1 = (((l >> 4) + 4) ^ (l & 7)) * 8;

  f32x4 acc[8][4] = {};

#define STAGE_A2(tile, half, bufc) do {                                        \
    const u16* s_ = sA + (size_t)(half) * 128 * K_TOT + (size_t)(tile) * 64;   \
    const int d_ = (bufc) * 32768 + (half) * 8192 + stq;                       \
    gload_lds16(s_, &lds[d_]);                                                 \
    gload_lds16(s_ + (size_t)64 * K_TOT, &lds[d_ + 4096]);                     \
  } while (0)
#define STAGE_B2(tile, half, bufc) do {                                        \
    const u16* s_ = sB + (size_t)(half) * 128 * K_TOT + (size_t)(tile) * 64;   \
    const int d_ = (bufc) * 32768 + 16384 + (half) * 8192 + stq;               \
    gload_lds16(s_, &lds[d_]);                                                 \
    gload_lds16(s_ + (size_t)64 * K_TOT, &lds[d_ + 4096]);                     \
  } while (0)

  // prologue: tile0 full + tile1 {B0,B1,A0}; wait tile0 landed (vmcnt(6))
  STAGE_B2(0, 0, 0); STAGE_B2(0, 1, 0); STAGE_A2(0, 0, 0); STAGE_A2(0, 1, 0);
  STAGE_B2(1, 0, 1); STAGE_B2(1, 1, 1); STAGE_A2(1, 0, 1);
  __builtin_amdgcn_sched_barrier(0);
  asm volatile("s_waitcnt vmcnt(6)");
  PHASE_BAR();

#define DO_TILE(TT, BUFC) do {                                                 \
    const int aoff_ = (BUFC) * 32768 + wm * 8192;                              \
    const int boff_ = (BUFC) * 32768 + 16384 + (wn >> 1) * 8192 + (wn & 1) * 4096; \
    bf16x8 af[4][2], b0f[2][2], b1f[2][2];                                     \
    /* P1: reads af-mh0 (8) + b0f (4); stage A1(t+1)->buf^1; BAR; MFMA (0,0) */ \
    _Pragma("unroll")                                                          \
    for (int m = 0; m < 4; ++m) {                                              \
      af[m][0] = *(const bf16x8*)&lds[aoff_ + m * 1024 + arow + c0];           \
      af[m][1] = *(const bf16x8*)&lds[aoff_ + m * 1024 + arow + c1];           \
    }                                                                          \
    _Pragma("unroll")                                                          \
    for (int n = 0; n < 2; ++n) {                                              \
      b0f[n][0] = *(const bf16x8*)&lds[boff_ + n * 1024 + arow + c0];          \
      b0f[n][1] = *(const bf16x8*)&lds[boff_ + n * 1024 + arow + c1];          \
    }                                                                          \
    if ((TT) + 1 < NT) STAGE_A2((TT) + 1, 1, (BUFC) ^ 1);                      \
    PHASE_BAR(); LGKM0();                                                      \
    __builtin_amdgcn_s_setprio(1);                                             \
    _Pragma("unroll")                                                          \
    for (int m = 0; m < 4; ++m)                                                \
      _Pragma("unroll")                                                        \
      for (int n = 0; n < 2; ++n) {                                            \
        acc[m][n] = MFMA16(af[m][0], b0f[n][0], acc[m][n], 0, 0, 0);           \
        acc[m][n] = MFMA16(af[m][1], b0f[n][1], acc[m][n], 0, 0, 0);           \
      }                                                                        \
    __builtin_amdgcn_s_setprio(0);                                             \
    /* P2: reads b1f (4); no stage; BAR; MFMA (0,1) */                         \
    _Pragma("unroll")                                                          \
    for (int n = 0; n < 2; ++n) {                                              \
      b1f[n][0] = *(const bf16x8*)&lds[boff_ + (n + 2) * 1024 + arow + c0];    \
      b1f[n][1] = *(const bf16x8*)&lds[boff_ + (n + 2) * 1024 + arow + c1];    \
    }                                                                          \
    PHASE_BAR(); LGKM0();                                                      \
    __builtin_amdgcn_s_setprio(1);                                             \
    _Pragma("unroll")                                                          \
    for (int m = 0; m < 4; ++m)                                                \
      _Pragma("unroll")                                                        \
      for (int n = 0; n < 2; ++n) {                                            \
        acc[m][n + 2] = MFMA16(af[m][0], b1f[n][0], acc[m][n + 2], 0, 0, 0);   \
        acc[m][n + 2] = MFMA16(af[m][1], b1f[n][1], acc[m][n + 2], 0, 0, 0);   \
      }                                                                        \
    __builtin_amdgcn_s_setprio(0);                                             \
    /* P3: reads af-mh1 (8); stage B0(t+2); BAR; MFMA (1,1) */                 \
    _Pragma("unroll")                                                          \
    for (int m = 0; m < 4; ++m) {                                              \
      af[m][0] = *(const bf16x8*)&lds[aoff_ + 4096 + m * 1024 + arow + c0];    \
      af[m][1] = *(const bf16x8*)&lds[aoff_ + 4096 + m * 1024 + arow + c1];    \
    }                                                                          \
    if ((TT) + 2 < NT) STAGE_B2((TT) + 2, 0, (BUFC));                          \
    PHASE_BAR(); LGKM0();                                                      \
    __builtin_amdgcn_s_setprio(1);                                             \
    _Pragma("unroll")                                                          \
    for (int m = 0; m < 4; ++m)                                                \
      _Pragma("unroll")                                                        \
      for (int n = 0; n < 2; ++n) {                                            \
        acc[m + 4][n + 2] = MFMA16(af[m][0], b1f[n][0], acc[m + 4][n + 2], 0, 0, 0); \
        acc[m + 4][n + 2] = MFMA16(af[m][1], b1f[n][1], acc[m + 4][n + 2], 0, 0, 0); \
      }                                                                        \
    __builtin_amdgcn_s_setprio(0);                                             \
    /* P4: no reads; stage B1(t+2)+A0(t+2); vmcnt(6); BAR; MFMA (1,0) */       \
    if ((TT) + 2 < NT) {                                                       \
      STAGE_B2((TT) + 2, 1, (BUFC));                                           \
      STAGE_A2((TT) + 2, 0, (BUFC));                                           \
      __builtin_amdgcn_sched_barrier(0);                                       \
      asm volatile("s_waitcnt vmcnt(6)");                                      \
    } else {                                                                   \
      asm volatile("s_waitcnt vmcnt(0)");                                      \
    }                                                                          \
    PHASE_BAR();                                                               \
    __builtin_amdgcn_s_setprio(1);                                             \
    _Pragma("unroll")                                                          \
    for (int m = 0; m < 4; ++m)                                                \
      _Pragma("unroll")                                                        \
      for (int n = 0; n < 2; ++n) {                                            \
        acc[m + 4][n] = MFMA16(af[m][0], b0f[n][0], acc[m + 4][n], 0, 0, 0);   \
        acc[m + 4][n] = MFMA16(af[m][1], b0f[n][1], acc[m + 4][n], 0, 0, 0);   \
      }                                                                        \
    __builtin_amdgcn_s_setprio(0);                                             \
  } while (0)

  for (int t = 0; t < NT; t += 2) {
    DO_TILE(t, 0);
    DO_TILE(t + 1, 1);
  }

  // ---- epilogue: C/D layout col=lane&15, row=(lane>>4)*4+reg ----
  const int colBase = bn * 256 + wn * 64 + (l & 15);
  float bv[4];
#pragma unroll
  for (int n = 0; n < 4; ++n) bv[n] = bias[colBase + n * 16];
#pragma unroll
  for (int mi = 0; mi < 8; ++mi) {
    const int row = bm * 256 + wm * 128 + mi * 16 + (l >> 4) * 4;
#pragma unroll
    for (int j = 0; j < 4; ++j) {
      float* orow = out + (size_t)(row + j) * N_OUT + colBase;
#pragma unroll
      for (int n = 0; n < 4; ++n) orow[n * 16] = acc[mi][n][j] + bv[n];
    }
  }
}

extern "C" void kernel_launch(void* const* d_in, const int* in_sizes, int n_in,
                              void* d_out, int out_size, void* d_ws, size_t ws_size,
                              hipStream_t stream) {
  const float* x  = (const float*)d_in[0];
  const float* Wb = (const float*)d_in[1];
  const float* bb = (const float*)d_in[2];
  const float* Am = (const float*)d_in[3];
  const float* Bm = (const float*)d_in[4];
  const float* Wr = (const float*)d_in[5];
  const int* topk = (const int*)d_in[6];
  float* out = (float*)d_out;

  u16* Xa  = (u16*)d_ws;                          // 8192*5120 bf16
  u16* Wa  = Xa + (size_t)M_TOT * K_TOT;          // 4096*5120 bf16
  u16* Msp = Wa + (size_t)N_OUT * K_TOT;          // 64*96*64 bf16 (786 KB)

  (void)hipFuncSetAttribute((const void*)gemm_aug,
                            hipFuncAttributeMaxDynamicSharedMemorySize, 131072);

  hipLaunchKernelGGL(build_msp,  dim3(96),           dim3(256), 0, stream,
                     Wr, Am, Msp);
  hipLaunchKernelGGL(prep_fused, dim3(128 + N_OUT / 2), dim3(512), 0, stream,
                     x, Msp, topk, Wb, Bm, Xa, Wa);
  hipLaunchKernelGGL(gemm_aug,   dim3(512),          dim3(512), 131072, stream,
                     Xa, Wa, bb, out);
}